// Round 4
// baseline (1349.850 us; speedup 1.0000x reference)
//
#include <hip/hip_runtime.h>

#define NB 2
#define NN 1024
#define HID 512
#define NHD 8
#define HD 64
#define NE 16

typedef float f4 __attribute__((ext_vector_type(4)));
typedef float f2 __attribute__((ext_vector_type(2)));

// ---- K0: mask dtype detection: 0=int32, 1=uint8-packed, 2=fp32, 3=int64 ----
__global__ __launch_bounds__(256) void k_maskdet(const unsigned int* __restrict__ m,
                                                 int* __restrict__ flag) {
    __shared__ int sh;
    if (threadIdx.x == 0) sh = 0;
    __syncthreads();
    int loc = 0;
    for (int i = threadIdx.x; i < 4096; i += 256) {  // 16 KB prefix, in-bounds for all encodings
        unsigned v = m[i];
        if (v == 0x3F800000u) loc |= 1;              // fp32 1.0 marker
        else if (v > 1u) loc |= 2;                   // packed-byte marker
        else if (v != 0u) loc |= (i & 1) ? 4 : 8;    // nonzero at odd / even word index
    }
    if (loc) atomicOr(&sh, loc);
    __syncthreads();
    if (threadIdx.x == 0) {
        int s = sh;
        int mode;
        if (s & 1) mode = 2;                          // fp32
        else if (s & 2) mode = 1;                     // uint8
        else if ((s & 8) && !(s & 4)) mode = 3;       // int64: ones only in (even) low words
        else mode = 0;                                // int32
        *flag = mode;
    }
}

__device__ __forceinline__ float eluf(float x) {
    return x > 0.f ? x : (__expf(x) - 1.f);
}

// ---- tiled 64x64 GEMM core: X(2048x512) @ W(512x512), 4x4 per thread ------
__device__ __forceinline__ void gemm_tile_512(
    const float* __restrict__ X, const float* __restrict__ W,
    int m0, int n0, float* xs, float4 acc[4]) {
    int tid = threadIdx.x;
    int tn = tid & 15, tm = tid >> 4;
    acc[0] = make_float4(0.f, 0.f, 0.f, 0.f);
    acc[1] = acc[0]; acc[2] = acc[0]; acc[3] = acc[0];
    for (int kc = 0; kc < 512; kc += 64) {
        __syncthreads();
#pragma unroll
        for (int j = 0; j < 4; j++) {
            int ml = tm + 16 * j;
            *(float4*)(xs + ml * 64 + tn * 4) =
                *(const float4*)(X + (size_t)(m0 + ml) * 512 + kc + tn * 4);
        }
        __syncthreads();
#pragma unroll 4
        for (int k4 = 0; k4 < 16; k4++) {
            float4 x0 = *(const float4*)(xs + (tm * 4 + 0) * 64 + k4 * 4);
            float4 x1 = *(const float4*)(xs + (tm * 4 + 1) * 64 + k4 * 4);
            float4 x2 = *(const float4*)(xs + (tm * 4 + 2) * 64 + k4 * 4);
            float4 x3 = *(const float4*)(xs + (tm * 4 + 3) * 64 + k4 * 4);
            const float* wr = W + (size_t)(kc + k4 * 4) * 512 + n0 + tn * 4;
#pragma unroll
            for (int kk = 0; kk < 4; kk++) {
                float4 w = *(const float4*)(wr + (size_t)kk * 512);
                float a0 = (kk == 0) ? x0.x : (kk == 1) ? x0.y : (kk == 2) ? x0.z : x0.w;
                float a1 = (kk == 0) ? x1.x : (kk == 1) ? x1.y : (kk == 2) ? x1.z : x1.w;
                float a2 = (kk == 0) ? x2.x : (kk == 1) ? x2.y : (kk == 2) ? x2.z : x2.w;
                float a3 = (kk == 0) ? x3.x : (kk == 1) ? x3.y : (kk == 2) ? x3.z : x3.w;
                acc[0].x += a0 * w.x; acc[0].y += a0 * w.y; acc[0].z += a0 * w.z; acc[0].w += a0 * w.w;
                acc[1].x += a1 * w.x; acc[1].y += a1 * w.y; acc[1].z += a1 * w.z; acc[1].w += a1 * w.w;
                acc[2].x += a2 * w.x; acc[2].y += a2 * w.y; acc[2].z += a2 * w.z; acc[2].w += a2 * w.w;
                acc[3].x += a3 * w.x; acc[3].y += a3 * w.y; acc[3].z += a3 * w.z; acc[3].w += a3 * w.w;
            }
        }
    }
}

// ---- K1: QKV projections, tiled. Q,V -> (b,h,tok,d); K -> K^T (b,h,d,tok) -
__global__ __launch_bounds__(256) void k_qkv_t(
    const float* __restrict__ x,
    const float* __restrict__ Wq, const float* __restrict__ Wk, const float* __restrict__ Wv,
    const float* __restrict__ bq, const float* __restrict__ bk, const float* __restrict__ bv,
    float* __restrict__ qb, float* __restrict__ kt, float* __restrict__ vb) {
    __shared__ __align__(16) float xs[64 * 64];
    int bx = blockIdx.x;
    int which = bx >> 8; bx &= 255;
    int m0 = (bx >> 3) * 64, n0 = (bx & 7) * 64;
    const float* W    = (which == 0) ? Wq : (which == 1) ? Wk : Wv;
    const float* bias = (which == 0) ? bq : (which == 1) ? bk : bv;
    float4 acc[4];
    gemm_tile_512(x, W, m0, n0, xs, acc);
    int tn = threadIdx.x & 15, tm = threadIdx.x >> 4;
    float4 bv4 = *(const float4*)(bias + n0 + tn * 4);
    int hh = n0 >> 6, d = tn * 4;        // n0 is 64-aligned -> single head per tile
#pragma unroll
    for (int r = 0; r < 4; r++) {
        int m = m0 + tm * 4 + r;
        int b = m >> 10, tok = m & 1023;
        float4 v = acc[r];
        v.x += bv4.x; v.y += bv4.y; v.z += bv4.z; v.w += bv4.w;
        if (which == 1) {
            // K^T: (b,h,d,tok)
            float* kth = kt + (size_t)(b * NHD + hh) * (HD * NN);
            kth[(size_t)(d + 0) * NN + tok] = v.x;
            kth[(size_t)(d + 1) * NN + tok] = v.y;
            kth[(size_t)(d + 2) * NN + tok] = v.z;
            kth[(size_t)(d + 3) * NN + tok] = v.w;
        } else {
            float* out = (which == 0) ? qb : vb;
            *(float4*)(out + (((size_t)(b * NHD + hh) * NN + tok) * HD + d)) = v;
        }
    }
}

// 16-term dot of e[] with a w1t row held in 4 float4s
#define DOT16(E, R)                                                            \
    fmaf(E[15], wD.w, fmaf(E[14], wD.z, fmaf(E[13], wD.y, fmaf(E[12], wD.x,    \
    fmaf(E[11], wC.w, fmaf(E[10], wC.z, fmaf(E[9],  wC.y, fmaf(E[8],  wC.x,    \
    fmaf(E[7],  wB.w, fmaf(E[6],  wB.z, fmaf(E[5],  wB.y, fmaf(E[4],  wB.x,    \
    fmaf(E[3],  wA.w, fmaf(E[2],  wA.z, fmaf(E[1],  wA.y, fmaf(E[0],  wA.x, R))))))))))))))))

// 2-col QK accumulate: one q float4 against 4 d-rows (float2 each)
#define QK2(QV, A0, A1)                                                        \
    A0 = fmaf(QV.x, k0v.x, fmaf(QV.y, k1v.x, fmaf(QV.z, k2v.x, fmaf(QV.w, k3v.x, A0)))); \
    A1 = fmaf(QV.x, k0v.y, fmaf(QV.y, k1v.y, fmaf(QV.z, k2v.y, fmaf(QV.w, k3v.y, A1))));

// ---- K2: FUSED edge-MLP bias (head-shared) + QK^T + mask -> UNNORMALIZED exp
// 8 tiles of 128 k-cols. MLP: 1 eval/thread (no spill). QK: 2 k-cols/lane.
// Softmax normalization deferred to k_av2 (which reads every row anyway).
__global__ __launch_bounds__(512, 2) void k_fscore(
    const float* __restrict__ qb, const float* __restrict__ kt,
    const float* __restrict__ ef,
    const float* __restrict__ We1, const float* __restrict__ be1,
    const float* __restrict__ We2, const float* __restrict__ be2,
    const void* __restrict__ mask, const int* __restrict__ mode_p,
    float* __restrict__ attn) {
    __shared__ __align__(16) float w1t[16][16];      // [o][f]  (transposed We1)
    __shared__ __align__(16) float w2[16][8];        // [o][h]
    __shared__ __align__(16) float b1s[16];
    __shared__ __align__(16) float b2s[8];
    __shared__ __align__(16) float qs[8][4][64];     // 8 KB
    __shared__ __align__(16) float biasS[8][4][128]; // 16 KB (per-tile bias, masked)
    int tid = threadIdx.x;
    if (tid < 256) w1t[tid & 15][tid >> 4] = We1[tid];
    else if (tid < 384) { int u = tid - 256; w2[u >> 3][u & 7] = We2[u]; }
    else if (tid < 400) b1s[tid - 384] = be1[tid - 384];
    else if (tid < 408) b2s[tid - 400] = be2[tid - 400];

    // XCD-aware swizzle: each XCD gets 64 contiguous logical blocks (one b per XCD)
    int bid = blockIdx.x;
    int lb = (bid & 7) * 64 + (bid >> 3);
    int b = lb >> 8, q0 = (lb & 255) * 4;

    {   // load Q[8h][4q][64d]
        int h = tid >> 6, q = (tid >> 4) & 3, c = tid & 15;
        *(float4*)(&qs[h][q][4 * c]) =
            *(const float4*)(qb + (((size_t)(b * NHD + h) * NN + q0 + q) * HD + 4 * c));
    }
    __syncthreads();
    int mode = *mode_p;
    int wv = tid >> 6, lane = tid & 63;
    const float* kth = kt + (size_t)(b * NHD + wv) * (HD * NN);  // [d][tok]
    int mq = tid >> 7, mk = tid & 127;                           // MLP assignment
    const float* efq = ef + (((size_t)b * NN) + q0 + mq) * (NN * NE);
    size_t mrow = (((size_t)b * NN) + q0 + mq) * NN;
    size_t arow = ((size_t)(b * NHD + wv) * NN + q0) * NN;       // q-stride = NN

    for (int t = 0; t < 8; t++) {
        int k0 = t * 128 + mk;
        // ---------- MLP phase: 1 eval/thread, on-the-fly layer-2 ----------
        {
            float e0[16];
            {
                const f4* pe0 = (const f4*)(efq + (size_t)k0 * NE);
#pragma unroll
                for (int c = 0; c < 4; c++) {
                    f4 v0 = __builtin_nontemporal_load(pe0 + c);   // streaming
                    e0[4*c+0]=v0.x; e0[4*c+1]=v0.y; e0[4*c+2]=v0.z; e0[4*c+3]=v0.w;
                }
            }
            float acc0[8];
#pragma unroll
            for (int j = 0; j < 8; j++) acc0[j] = b2s[j];
#pragma unroll
            for (int o = 0; o < 16; o++) {
                float4 wA = *(const float4*)(&w1t[o][0]);
                float4 wB = *(const float4*)(&w1t[o][4]);
                float4 wC = *(const float4*)(&w1t[o][8]);
                float4 wD = *(const float4*)(&w1t[o][12]);
                float a0 = DOT16(e0, b1s[o]);
                float g0v = eluf(a0);
                float4 u0 = *(const float4*)(&w2[o][0]);
                float4 u1 = *(const float4*)(&w2[o][4]);
                acc0[0] = fmaf(g0v, u0.x, acc0[0]); acc0[1] = fmaf(g0v, u0.y, acc0[1]);
                acc0[2] = fmaf(g0v, u0.z, acc0[2]); acc0[3] = fmaf(g0v, u0.w, acc0[3]);
                acc0[4] = fmaf(g0v, u1.x, acc0[4]); acc0[5] = fmaf(g0v, u1.y, acc0[5]);
                acc0[6] = fmaf(g0v, u1.z, acc0[6]); acc0[7] = fmaf(g0v, u1.w, acc0[7]);
            }
            size_t p0i = mrow + k0;
            bool m0;
            if (mode == 3)      m0 = ((const unsigned int*)mask)[2 * p0i] != 0u;
            else if (mode == 2) m0 = ((const float*)mask)[p0i] != 0.0f;
            else if (mode == 1) m0 = ((const unsigned char*)mask)[p0i] != 0;
            else                m0 = ((const int*)mask)[p0i] != 0;
#pragma unroll
            for (int hh = 0; hh < 8; hh++)
                biasS[hh][mq][mk] = m0 ? -1e30f : acc0[hh];
        }
        __syncthreads();
        // ---------- QK phase: wave = head; lane covers 2 consecutive k ------
        {
            float a00=0.f,a01=0.f, a10=0.f,a11=0.f, a20=0.f,a21=0.f, a30=0.f,a31=0.f;
            const float* kb0 = kth + t * 128 + 2 * lane;
#pragma unroll
            for (int dc = 0; dc < 16; dc++) {
                float4 qv0 = *(const float4*)(&qs[wv][0][dc * 4]);
                float4 qv1 = *(const float4*)(&qs[wv][1][dc * 4]);
                float4 qv2 = *(const float4*)(&qs[wv][2][dc * 4]);
                float4 qv3 = *(const float4*)(&qs[wv][3][dc * 4]);
                float2 k0v = *(const float2*)(kb0 + (size_t)(dc * 4 + 0) * NN);
                float2 k1v = *(const float2*)(kb0 + (size_t)(dc * 4 + 1) * NN);
                float2 k2v = *(const float2*)(kb0 + (size_t)(dc * 4 + 2) * NN);
                float2 k3v = *(const float2*)(kb0 + (size_t)(dc * 4 + 3) * NN);
                QK2(qv0, a00, a01);
                QK2(qv1, a10, a11);
                QK2(qv2, a20, a21);
                QK2(qv3, a30, a31);
            }
            float2 b0 = *(const float2*)(&biasS[wv][0][2 * lane]);
            float2 b1 = *(const float2*)(&biasS[wv][1][2 * lane]);
            float2 b2 = *(const float2*)(&biasS[wv][2][2 * lane]);
            float2 b3 = *(const float2*)(&biasS[wv][3][2 * lane]);
            f2 p0, p1, p2, p3;
            p0.x = __expf(fmaf(a00, 0.125f, b0.x)); p0.y = __expf(fmaf(a01, 0.125f, b0.y));
            p1.x = __expf(fmaf(a10, 0.125f, b1.x)); p1.y = __expf(fmaf(a11, 0.125f, b1.y));
            p2.x = __expf(fmaf(a20, 0.125f, b2.x)); p2.y = __expf(fmaf(a21, 0.125f, b2.y));
            p3.x = __expf(fmaf(a30, 0.125f, b3.x)); p3.y = __expf(fmaf(a31, 0.125f, b3.y));
            size_t kc = (size_t)t * 128 + 2 * lane;
            __builtin_nontemporal_store(p0, (f2*)(attn + arow + 0 * NN + kc));
            __builtin_nontemporal_store(p1, (f2*)(attn + arow + 1 * NN + kc));
            __builtin_nontemporal_store(p2, (f2*)(attn + arow + 2 * NN + kc));
            __builtin_nontemporal_store(p3, (f2*)(attn + arow + 3 * NN + kc));
        }
        __syncthreads();
    }
}

// ---- K3: attn @ V with deferred softmax normalization ---------------------
// Wave per (b,h, 8 q-rows), lane = d.  Pass 1: accumulate AV and row sums
// (attn holds unnormalized exp).  Then scale AV by 1/sum and write oattn;
// pass 2 normalizes the attn rows in place (wave-owned, no races).
__global__ __launch_bounds__(256) void k_av2(
    float* __restrict__ attn, const float* __restrict__ vb,
    float* __restrict__ oattn) {
    int w = blockIdx.x * 4 + (threadIdx.x >> 6);
    int lane = threadIdx.x & 63;
    int bh = w >> 7;
    int q0 = (w & 127) * 8;
    float* ar = attn + ((size_t)bh * NN + q0) * NN;
    const float* vbh = vb + (size_t)bh * (NN * HD);
    float acc[8] = {0.f, 0.f, 0.f, 0.f, 0.f, 0.f, 0.f, 0.f};
    float sum[8] = {0.f, 0.f, 0.f, 0.f, 0.f, 0.f, 0.f, 0.f};
#pragma unroll 2
    for (int k = 0; k < NN; k += 4) {
        float4 a[8];
#pragma unroll
        for (int r = 0; r < 8; r++) a[r] = *(const float4*)(ar + (size_t)r * NN + k);
        float v0 = vbh[(k + 0) * HD + lane];
        float v1 = vbh[(k + 1) * HD + lane];
        float v2 = vbh[(k + 2) * HD + lane];
        float v3 = vbh[(k + 3) * HD + lane];
#pragma unroll
        for (int r = 0; r < 8; r++) {
            acc[r] += a[r].x * v0;
            acc[r] += a[r].y * v1;
            acc[r] += a[r].z * v2;
            acc[r] += a[r].w * v3;
            sum[r] += (a[r].x + a[r].y) + (a[r].z + a[r].w);
        }
    }
    int b = bh >> 3, hh = bh & 7;
#pragma unroll
    for (int r = 0; r < 8; r++) {
        float inv = (sum[r] > 0.f) ? 1.f / sum[r] : 0.f;   // fully-masked -> zeros
        oattn[(size_t)(b * NN + q0 + r) * HID + hh * 64 + lane] = acc[r] * inv;
        // pass 2: normalize this attn row in place (L2-hot from pass 1)
        float* row = ar + (size_t)r * NN;
        for (int k = 4 * lane; k < NN; k += 256) {
            f4 v = *(const f4*)(row + k);
            v.x *= inv; v.y *= inv; v.z *= inv; v.w *= inv;
            __builtin_nontemporal_store(v, (f4*)(row + k));
        }
    }
}

// ---- K4: output projection, tiled --------------------------------------
__global__ __launch_bounds__(256) void k_oproj_t(
    const float* __restrict__ oa, const float* __restrict__ Wo,
    const float* __restrict__ bo, float* __restrict__ out) {
    __shared__ __align__(16) float xs[64 * 64];
    int bx = blockIdx.x;
    int m0 = (bx >> 3) * 64, n0 = (bx & 7) * 64;
    float4 acc[4];
    gemm_tile_512(oa, Wo, m0, n0, xs, acc);
    int tn = threadIdx.x & 15, tm = threadIdx.x >> 4;
    float4 bv4 = *(const float4*)(bo + n0 + tn * 4);
#pragma unroll
    for (int r = 0; r < 4; r++) {
        int m = m0 + tm * 4 + r;
        float4 v = acc[r];
        v.x += bv4.x; v.y += bv4.y; v.z += bv4.z; v.w += bv4.w;
        *(float4*)(out + (size_t)m * HID + n0 + tn * 4) = v;
    }
}

extern "C" void kernel_launch(void* const* d_in, const int* in_sizes, int n_in,
                              void* d_out, int out_size, void* d_ws, size_t ws_size,
                              hipStream_t stream) {
    (void)in_sizes; (void)n_in; (void)out_size; (void)ws_size;
    const float* x   = (const float*)d_in[0];
    const float* ef  = (const float*)d_in[1];
    const void*  msk = d_in[2];
    const float* Wq  = (const float*)d_in[3];
    const float* bq  = (const float*)d_in[4];
    const float* Wk  = (const float*)d_in[5];
    const float* bk  = (const float*)d_in[6];
    const float* Wv  = (const float*)d_in[7];
    const float* bv  = (const float*)d_in[8];
    const float* Wo  = (const float*)d_in[9];
    const float* bo  = (const float*)d_in[10];
    const float* We1 = (const float*)d_in[11];
    const float* be1 = (const float*)d_in[12];
    const float* We2 = (const float*)d_in[13];
    const float* be2 = (const float*)d_in[14];

    char* ws = (char*)d_ws;
    float* qb    = (float*)(ws + 0);          // 4 MB  (b,h,tok,d)
    float* kt    = (float*)(ws + 4194304);    // 4 MB  K^T (b,h,d,tok)
    float* vb    = (float*)(ws + 8388608);    // 4 MB  (b,h,tok,d)
    float* oattn = (float*)(ws + 12582912);   // 4 MB  (b,tok, h*64+d)
    int*   flag  = (int*)(ws + 16777216);     // 4 B

    float* out0 = (float*)d_out;
    float* attn = out0 + (size_t)NB * NN * HID;  // output 1: (B,H,N,N) fp32

    k_maskdet<<<1, 256, 0, stream>>>((const unsigned int*)msk, flag);
    k_qkv_t<<<768, 256, 0, stream>>>(x, Wq, Wk, Wv, bq, bk, bv, qb, kt, vb);
    k_fscore<<<512, 512, 0, stream>>>(qb, kt, ef, We1, be1, We2, be2, msk, flag, attn);
    k_av2<<<512, 256, 0, stream>>>(attn, vb, oattn);
    k_oproj_t<<<256, 256, 0, stream>>>(oattn, Wo, bo, out0);
}

// Round 5
// 1006.870 us; speedup vs baseline: 1.3406x; 1.3406x over previous
//
#include <hip/hip_runtime.h>

#define NB 2
#define NN 1024
#define HID 512
#define NHD 8
#define HD 64
#define NE 16

typedef float f4 __attribute__((ext_vector_type(4)));

// ---- K0: mask dtype detection: 0=int32, 1=uint8-packed, 2=fp32, 3=int64 ----
__global__ __launch_bounds__(256) void k_maskdet(const unsigned int* __restrict__ m,
                                                 int* __restrict__ flag) {
    __shared__ int sh;
    if (threadIdx.x == 0) sh = 0;
    __syncthreads();
    int loc = 0;
    for (int i = threadIdx.x; i < 4096; i += 256) {  // 16 KB prefix, in-bounds for all encodings
        unsigned v = m[i];
        if (v == 0x3F800000u) loc |= 1;              // fp32 1.0 marker
        else if (v > 1u) loc |= 2;                   // packed-byte marker
        else if (v != 0u) loc |= (i & 1) ? 4 : 8;    // nonzero at odd / even word index
    }
    if (loc) atomicOr(&sh, loc);
    __syncthreads();
    if (threadIdx.x == 0) {
        int s = sh;
        int mode;
        if (s & 1) mode = 2;                          // fp32
        else if (s & 2) mode = 1;                     // uint8
        else if ((s & 8) && !(s & 4)) mode = 3;       // int64: ones only in (even) low words
        else mode = 0;                                // int32
        *flag = mode;
    }
}

__device__ __forceinline__ float eluf(float x) {
    return x > 0.f ? x : (__expf(x) - 1.f);
}

// ---- tiled 64x64 GEMM core: X(2048x512) @ W(512x512), 4x4 per thread ------
__device__ __forceinline__ void gemm_tile_512(
    const float* __restrict__ X, const float* __restrict__ W,
    int m0, int n0, float* xs, float4 acc[4]) {
    int tid = threadIdx.x;
    int tn = tid & 15, tm = tid >> 4;
    acc[0] = make_float4(0.f, 0.f, 0.f, 0.f);
    acc[1] = acc[0]; acc[2] = acc[0]; acc[3] = acc[0];
    for (int kc = 0; kc < 512; kc += 64) {
        __syncthreads();
#pragma unroll
        for (int j = 0; j < 4; j++) {
            int ml = tm + 16 * j;
            *(float4*)(xs + ml * 64 + tn * 4) =
                *(const float4*)(X + (size_t)(m0 + ml) * 512 + kc + tn * 4);
        }
        __syncthreads();
#pragma unroll 4
        for (int k4 = 0; k4 < 16; k4++) {
            float4 x0 = *(const float4*)(xs + (tm * 4 + 0) * 64 + k4 * 4);
            float4 x1 = *(const float4*)(xs + (tm * 4 + 1) * 64 + k4 * 4);
            float4 x2 = *(const float4*)(xs + (tm * 4 + 2) * 64 + k4 * 4);
            float4 x3 = *(const float4*)(xs + (tm * 4 + 3) * 64 + k4 * 4);
            const float* wr = W + (size_t)(kc + k4 * 4) * 512 + n0 + tn * 4;
#pragma unroll
            for (int kk = 0; kk < 4; kk++) {
                float4 w = *(const float4*)(wr + (size_t)kk * 512);
                float a0 = (kk == 0) ? x0.x : (kk == 1) ? x0.y : (kk == 2) ? x0.z : x0.w;
                float a1 = (kk == 0) ? x1.x : (kk == 1) ? x1.y : (kk == 2) ? x1.z : x1.w;
                float a2 = (kk == 0) ? x2.x : (kk == 1) ? x2.y : (kk == 2) ? x2.z : x2.w;
                float a3 = (kk == 0) ? x3.x : (kk == 1) ? x3.y : (kk == 2) ? x3.z : x3.w;
                acc[0].x += a0 * w.x; acc[0].y += a0 * w.y; acc[0].z += a0 * w.z; acc[0].w += a0 * w.w;
                acc[1].x += a1 * w.x; acc[1].y += a1 * w.y; acc[1].z += a1 * w.z; acc[1].w += a1 * w.w;
                acc[2].x += a2 * w.x; acc[2].y += a2 * w.y; acc[2].z += a2 * w.z; acc[2].w += a2 * w.w;
                acc[3].x += a3 * w.x; acc[3].y += a3 * w.y; acc[3].z += a3 * w.z; acc[3].w += a3 * w.w;
            }
        }
    }
}

// ---- K1: QKV projections, tiled. Q,V -> (b,h,tok,d); K -> K^T (b,h,d,tok) -
__global__ __launch_bounds__(256) void k_qkv_t(
    const float* __restrict__ x,
    const float* __restrict__ Wq, const float* __restrict__ Wk, const float* __restrict__ Wv,
    const float* __restrict__ bq, const float* __restrict__ bk, const float* __restrict__ bv,
    float* __restrict__ qb, float* __restrict__ kt, float* __restrict__ vb) {
    __shared__ __align__(16) float xs[64 * 64];
    int bx = blockIdx.x;
    int which = bx >> 8; bx &= 255;
    int m0 = (bx >> 3) * 64, n0 = (bx & 7) * 64;
    const float* W    = (which == 0) ? Wq : (which == 1) ? Wk : Wv;
    const float* bias = (which == 0) ? bq : (which == 1) ? bk : bv;
    float4 acc[4];
    gemm_tile_512(x, W, m0, n0, xs, acc);
    int tn = threadIdx.x & 15, tm = threadIdx.x >> 4;
    float4 bv4 = *(const float4*)(bias + n0 + tn * 4);
    int hh = n0 >> 6, d = tn * 4;        // n0 is 64-aligned -> single head per tile
#pragma unroll
    for (int r = 0; r < 4; r++) {
        int m = m0 + tm * 4 + r;
        int b = m >> 10, tok = m & 1023;
        float4 v = acc[r];
        v.x += bv4.x; v.y += bv4.y; v.z += bv4.z; v.w += bv4.w;
        if (which == 1) {
            // K^T: (b,h,d,tok)
            float* kth = kt + (size_t)(b * NHD + hh) * (HD * NN);
            kth[(size_t)(d + 0) * NN + tok] = v.x;
            kth[(size_t)(d + 1) * NN + tok] = v.y;
            kth[(size_t)(d + 2) * NN + tok] = v.z;
            kth[(size_t)(d + 3) * NN + tok] = v.w;
        } else {
            float* out = (which == 0) ? qb : vb;
            *(float4*)(out + (((size_t)(b * NHD + hh) * NN + tok) * HD + d)) = v;
        }
    }
}

// dot-accumulate: 4 q-scalars (one f4) x 4 k-columns across 4 d's
#define QKACC(QV, A0, A1, A2, A3)                                              \
    A0 = fmaf(QV.x, k0v.x, fmaf(QV.y, k1v.x, fmaf(QV.z, k2v.x, fmaf(QV.w, k3v.x, A0)))); \
    A1 = fmaf(QV.x, k0v.y, fmaf(QV.y, k1v.y, fmaf(QV.z, k2v.y, fmaf(QV.w, k3v.y, A1)))); \
    A2 = fmaf(QV.x, k0v.z, fmaf(QV.y, k1v.z, fmaf(QV.z, k2v.z, fmaf(QV.w, k3v.z, A2)))); \
    A3 = fmaf(QV.x, k0v.w, fmaf(QV.y, k1v.w, fmaf(QV.z, k2v.w, fmaf(QV.w, k3v.w, A3))));

// 16-term dot of e[] with a w1t row held in 4 float4s
#define DOT16(E, R)                                                            \
    fmaf(E[15], wD.w, fmaf(E[14], wD.z, fmaf(E[13], wD.y, fmaf(E[12], wD.x,    \
    fmaf(E[11], wC.w, fmaf(E[10], wC.z, fmaf(E[9],  wC.y, fmaf(E[8],  wC.x,    \
    fmaf(E[7],  wB.w, fmaf(E[6],  wB.z, fmaf(E[5],  wB.y, fmaf(E[4],  wB.x,    \
    fmaf(E[3],  wA.w, fmaf(E[2],  wA.z, fmaf(E[1],  wA.y, fmaf(E[0],  wA.x, R))))))))))))))))

// ---- K2: FUSED edge-MLP bias (head-shared) + QK^T + mask -> UNNORMALIZED exp
// 4 tiles of 256 k-cols. UNCAPPED registers (launch_bounds(512,1) -> up to
// 256 VGPR, 1 block/CU): the 128-cap was causing 1.5-2.5 GB of spill traffic.
// Softmax normalization deferred to k_av2 (which reads every row anyway).
__global__ __launch_bounds__(512, 1) void k_fscore(
    const float* __restrict__ qb, const float* __restrict__ kt,
    const float* __restrict__ ef,
    const float* __restrict__ We1, const float* __restrict__ be1,
    const float* __restrict__ We2, const float* __restrict__ be2,
    const void* __restrict__ mask, const int* __restrict__ mode_p,
    float* __restrict__ attn) {
    __shared__ __align__(16) float w1t[16][16];      // [o][f]  (transposed We1)
    __shared__ __align__(16) float w2[16][8];        // [o][h]
    __shared__ __align__(16) float b1s[16];
    __shared__ __align__(16) float b2s[8];
    __shared__ __align__(16) float qs[8][4][64];     // 8 KB
    __shared__ __align__(16) float biasS[8][4][256]; // 32 KB (per-tile bias, masked)
    int tid = threadIdx.x;
    if (tid < 256) w1t[tid & 15][tid >> 4] = We1[tid];
    else if (tid < 384) { int u = tid - 256; w2[u >> 3][u & 7] = We2[u]; }
    else if (tid < 400) b1s[tid - 384] = be1[tid - 384];
    else if (tid < 408) b2s[tid - 400] = be2[tid - 400];

    // XCD-aware swizzle: each XCD gets 64 contiguous logical blocks (one b per XCD)
    int bid = blockIdx.x;
    int lb = (bid & 7) * 64 + (bid >> 3);
    int b = lb >> 8, q0 = (lb & 255) * 4;

    {   // load Q[8h][4q][64d]
        int h = tid >> 6, q = (tid >> 4) & 3, c = tid & 15;
        *(float4*)(&qs[h][q][4 * c]) =
            *(const float4*)(qb + (((size_t)(b * NHD + h) * NN + q0 + q) * HD + 4 * c));
    }
    __syncthreads();
    int mode = *mode_p;
    int wv = tid >> 6, lane = tid & 63;
    const float* kth = kt + (size_t)(b * NHD + wv) * (HD * NN);  // [d][tok]
    int mq = tid >> 7, mk = tid & 127;                           // MLP assignment
    const float* efq = ef + (((size_t)b * NN) + q0 + mq) * (NN * NE);
    size_t mrow = (((size_t)b * NN) + q0 + mq) * NN;
    size_t arow = ((size_t)(b * NHD + wv) * NN + q0) * NN;       // q-stride = NN

    for (int t = 0; t < 4; t++) {
        int k0 = t * 256 + mk, k1 = k0 + 128;
        // ---------- MLP phase: 2 evals/thread, on-the-fly layer-2 ----------
        {
            float e0[16], e1[16];
            {
                const f4* pe0 = (const f4*)(efq + (size_t)k0 * NE);
                const f4* pe1 = (const f4*)(efq + (size_t)k1 * NE);
#pragma unroll
                for (int c = 0; c < 4; c++) {
                    f4 v0 = __builtin_nontemporal_load(pe0 + c);   // streaming
                    f4 v1 = __builtin_nontemporal_load(pe1 + c);
                    e0[4*c+0]=v0.x; e0[4*c+1]=v0.y; e0[4*c+2]=v0.z; e0[4*c+3]=v0.w;
                    e1[4*c+0]=v1.x; e1[4*c+1]=v1.y; e1[4*c+2]=v1.z; e1[4*c+3]=v1.w;
                }
            }
            float acc0[8], acc1[8];
#pragma unroll
            for (int j = 0; j < 8; j++) { acc0[j] = b2s[j]; acc1[j] = b2s[j]; }
#pragma unroll
            for (int o = 0; o < 16; o++) {
                float4 wA = *(const float4*)(&w1t[o][0]);
                float4 wB = *(const float4*)(&w1t[o][4]);
                float4 wC = *(const float4*)(&w1t[o][8]);
                float4 wD = *(const float4*)(&w1t[o][12]);
                float a0 = DOT16(e0, b1s[o]);
                float a1 = DOT16(e1, b1s[o]);
                float g0v = eluf(a0);
                float g1v = eluf(a1);
                float4 u0 = *(const float4*)(&w2[o][0]);
                float4 u1 = *(const float4*)(&w2[o][4]);
                acc0[0] = fmaf(g0v, u0.x, acc0[0]); acc0[1] = fmaf(g0v, u0.y, acc0[1]);
                acc0[2] = fmaf(g0v, u0.z, acc0[2]); acc0[3] = fmaf(g0v, u0.w, acc0[3]);
                acc0[4] = fmaf(g0v, u1.x, acc0[4]); acc0[5] = fmaf(g0v, u1.y, acc0[5]);
                acc0[6] = fmaf(g0v, u1.z, acc0[6]); acc0[7] = fmaf(g0v, u1.w, acc0[7]);
                acc1[0] = fmaf(g1v, u0.x, acc1[0]); acc1[1] = fmaf(g1v, u0.y, acc1[1]);
                acc1[2] = fmaf(g1v, u0.z, acc1[2]); acc1[3] = fmaf(g1v, u0.w, acc1[3]);
                acc1[4] = fmaf(g1v, u1.x, acc1[4]); acc1[5] = fmaf(g1v, u1.y, acc1[5]);
                acc1[6] = fmaf(g1v, u1.z, acc1[6]); acc1[7] = fmaf(g1v, u1.w, acc1[7]);
            }
            size_t p0i = mrow + k0, p1i = mrow + k1;
            bool m0, m1;
            if (mode == 3) {
                m0 = ((const unsigned int*)mask)[2 * p0i] != 0u;
                m1 = ((const unsigned int*)mask)[2 * p1i] != 0u;
            } else if (mode == 2) {
                m0 = ((const float*)mask)[p0i] != 0.0f;
                m1 = ((const float*)mask)[p1i] != 0.0f;
            } else if (mode == 1) {
                m0 = ((const unsigned char*)mask)[p0i] != 0;
                m1 = ((const unsigned char*)mask)[p1i] != 0;
            } else {
                m0 = ((const int*)mask)[p0i] != 0;
                m1 = ((const int*)mask)[p1i] != 0;
            }
#pragma unroll
            for (int hh = 0; hh < 8; hh++) {
                biasS[hh][mq][mk]       = m0 ? -1e30f : acc0[hh];
                biasS[hh][mq][mk + 128] = m1 ? -1e30f : acc1[hh];
            }
        }
        __syncthreads();
        // ---------- QK phase: wave = head; lane covers 4 consecutive k ------
        {
            float a00=0.f,a01=0.f,a02=0.f,a03=0.f, a10=0.f,a11=0.f,a12=0.f,a13=0.f;
            float a20=0.f,a21=0.f,a22=0.f,a23=0.f, a30=0.f,a31=0.f,a32=0.f,a33=0.f;
            const float* kb0 = kth + t * 256 + 4 * lane;
#pragma unroll
            for (int dc = 0; dc < 16; dc++) {
                float4 qv0 = *(const float4*)(&qs[wv][0][dc * 4]);
                float4 qv1 = *(const float4*)(&qs[wv][1][dc * 4]);
                float4 qv2 = *(const float4*)(&qs[wv][2][dc * 4]);
                float4 qv3 = *(const float4*)(&qs[wv][3][dc * 4]);
                float4 k0v = *(const float4*)(kb0 + (size_t)(dc * 4 + 0) * NN);
                float4 k1v = *(const float4*)(kb0 + (size_t)(dc * 4 + 1) * NN);
                float4 k2v = *(const float4*)(kb0 + (size_t)(dc * 4 + 2) * NN);
                float4 k3v = *(const float4*)(kb0 + (size_t)(dc * 4 + 3) * NN);
                QKACC(qv0, a00, a01, a02, a03);
                QKACC(qv1, a10, a11, a12, a13);
                QKACC(qv2, a20, a21, a22, a23);
                QKACC(qv3, a30, a31, a32, a33);
            }
            float4 bq0 = *(const float4*)(&biasS[wv][0][4 * lane]);
            float4 bq1 = *(const float4*)(&biasS[wv][1][4 * lane]);
            float4 bq2 = *(const float4*)(&biasS[wv][2][4 * lane]);
            float4 bq3 = *(const float4*)(&biasS[wv][3][4 * lane]);
            float4 p0, p1, p2, p3;
            p0.x = __expf(fmaf(a00, 0.125f, bq0.x)); p0.y = __expf(fmaf(a01, 0.125f, bq0.y));
            p0.z = __expf(fmaf(a02, 0.125f, bq0.z)); p0.w = __expf(fmaf(a03, 0.125f, bq0.w));
            p1.x = __expf(fmaf(a10, 0.125f, bq1.x)); p1.y = __expf(fmaf(a11, 0.125f, bq1.y));
            p1.z = __expf(fmaf(a12, 0.125f, bq1.z)); p1.w = __expf(fmaf(a13, 0.125f, bq1.w));
            p2.x = __expf(fmaf(a20, 0.125f, bq2.x)); p2.y = __expf(fmaf(a21, 0.125f, bq2.y));
            p2.z = __expf(fmaf(a22, 0.125f, bq2.z)); p2.w = __expf(fmaf(a23, 0.125f, bq2.w));
            p3.x = __expf(fmaf(a30, 0.125f, bq3.x)); p3.y = __expf(fmaf(a31, 0.125f, bq3.y));
            p3.z = __expf(fmaf(a32, 0.125f, bq3.z)); p3.w = __expf(fmaf(a33, 0.125f, bq3.w));
            size_t kc = (size_t)t * 256 + 4 * lane;
            *(float4*)(attn + arow + 0 * NN + kc) = p0;
            *(float4*)(attn + arow + 1 * NN + kc) = p1;
            *(float4*)(attn + arow + 2 * NN + kc) = p2;
            *(float4*)(attn + arow + 3 * NN + kc) = p3;
        }
        __syncthreads();
    }
}

// ---- K3: attn @ V with deferred softmax normalization ---------------------
// Wave per (b,h, 8 q-rows), lane = d.  Pass 1: accumulate AV and row sums
// (attn holds unnormalized exp).  Then scale AV by 1/sum and write oattn;
// pass 2 normalizes the attn rows in place (wave-owned, no races).
__global__ __launch_bounds__(256) void k_av2(
    float* __restrict__ attn, const float* __restrict__ vb,
    float* __restrict__ oattn) {
    int w = blockIdx.x * 4 + (threadIdx.x >> 6);
    int lane = threadIdx.x & 63;
    int bh = w >> 7;
    int q0 = (w & 127) * 8;
    float* ar = attn + ((size_t)bh * NN + q0) * NN;
    const float* vbh = vb + (size_t)bh * (NN * HD);
    float acc[8] = {0.f, 0.f, 0.f, 0.f, 0.f, 0.f, 0.f, 0.f};
    float sum[8] = {0.f, 0.f, 0.f, 0.f, 0.f, 0.f, 0.f, 0.f};
#pragma unroll 2
    for (int k = 0; k < NN; k += 4) {
        float4 a[8];
#pragma unroll
        for (int r = 0; r < 8; r++) a[r] = *(const float4*)(ar + (size_t)r * NN + k);
        float v0 = vbh[(k + 0) * HD + lane];
        float v1 = vbh[(k + 1) * HD + lane];
        float v2 = vbh[(k + 2) * HD + lane];
        float v3 = vbh[(k + 3) * HD + lane];
#pragma unroll
        for (int r = 0; r < 8; r++) {
            acc[r] += a[r].x * v0;
            acc[r] += a[r].y * v1;
            acc[r] += a[r].z * v2;
            acc[r] += a[r].w * v3;
            sum[r] += (a[r].x + a[r].y) + (a[r].z + a[r].w);
        }
    }
    int b = bh >> 3, hh = bh & 7;
#pragma unroll
    for (int r = 0; r < 8; r++) {
        float inv = (sum[r] > 0.f) ? 1.f / sum[r] : 0.f;   // fully-masked -> zeros
        oattn[(size_t)(b * NN + q0 + r) * HID + hh * 64 + lane] = acc[r] * inv;
        // pass 2: normalize this attn row in place (L2-hot from pass 1)
        float* row = ar + (size_t)r * NN;
        for (int k = 4 * lane; k < NN; k += 256) {
            float4 v = *(const float4*)(row + k);
            v.x *= inv; v.y *= inv; v.z *= inv; v.w *= inv;
            *(float4*)(row + k) = v;
        }
    }
}

// ---- K4: output projection, tiled --------------------------------------
__global__ __launch_bounds__(256) void k_oproj_t(
    const float* __restrict__ oa, const float* __restrict__ Wo,
    const float* __restrict__ bo, float* __restrict__ out) {
    __shared__ __align__(16) float xs[64 * 64];
    int bx = blockIdx.x;
    int m0 = (bx >> 3) * 64, n0 = (bx & 7) * 64;
    float4 acc[4];
    gemm_tile_512(oa, Wo, m0, n0, xs, acc);
    int tn = threadIdx.x & 15, tm = threadIdx.x >> 4;
    float4 bv4 = *(const float4*)(bo + n0 + tn * 4);
#pragma unroll
    for (int r = 0; r < 4; r++) {
        int m = m0 + tm * 4 + r;
        float4 v = acc[r];
        v.x += bv4.x; v.y += bv4.y; v.z += bv4.z; v.w += bv4.w;
        *(float4*)(out + (size_t)m * HID + n0 + tn * 4) = v;
    }
}

extern "C" void kernel_launch(void* const* d_in, const int* in_sizes, int n_in,
                              void* d_out, int out_size, void* d_ws, size_t ws_size,
                              hipStream_t stream) {
    (void)in_sizes; (void)n_in; (void)out_size; (void)ws_size;
    const float* x   = (const float*)d_in[0];
    const float* ef  = (const float*)d_in[1];
    const void*  msk = d_in[2];
    const float* Wq  = (const float*)d_in[3];
    const float* bq  = (const float*)d_in[4];
    const float* Wk  = (const float*)d_in[5];
    const float* bk  = (const float*)d_in[6];
    const float* Wv  = (const float*)d_in[7];
    const float* bv  = (const float*)d_in[8];
    const float* Wo  = (const float*)d_in[9];
    const float* bo  = (const float*)d_in[10];
    const float* We1 = (const float*)d_in[11];
    const float* be1 = (const float*)d_in[12];
    const float* We2 = (const float*)d_in[13];
    const float* be2 = (const float*)d_in[14];

    char* ws = (char*)d_ws;
    float* qb    = (float*)(ws + 0);          // 4 MB  (b,h,tok,d)
    float* kt    = (float*)(ws + 4194304);    // 4 MB  K^T (b,h,d,tok)
    float* vb    = (float*)(ws + 8388608);    // 4 MB  (b,h,tok,d)
    float* oattn = (float*)(ws + 12582912);   // 4 MB  (b,tok, h*64+d)
    int*   flag  = (int*)(ws + 16777216);     // 4 B

    float* out0 = (float*)d_out;
    float* attn = out0 + (size_t)NB * NN * HID;  // output 1: (B,H,N,N) fp32

    k_maskdet<<<1, 256, 0, stream>>>((const unsigned int*)msk, flag);
    k_qkv_t<<<768, 256, 0, stream>>>(x, Wq, Wk, Wv, bq, bk, bv, qb, kt, vb);
    k_fscore<<<512, 512, 0, stream>>>(qb, kt, ef, We1, be1, We2, be2, msk, flag, attn);
    k_av2<<<512, 256, 0, stream>>>(attn, vb, oattn);
    k_oproj_t<<<256, 256, 0, stream>>>(oattn, Wo, bo, out0);
}

// Round 6
// 695.748 us; speedup vs baseline: 1.9401x; 1.4472x over previous
//
#include <hip/hip_runtime.h>

#define NB 2
#define NN 1024
#define HID 512
#define NHD 8
#define HD 64
#define NE 16

typedef float f4 __attribute__((ext_vector_type(4)));
typedef float f2 __attribute__((ext_vector_type(2)));

// ---- K0: mask dtype detection: 0=int32, 1=uint8-packed, 2=fp32, 3=int64 ----
__global__ __launch_bounds__(256) void k_maskdet(const unsigned int* __restrict__ m,
                                                 int* __restrict__ flag) {
    __shared__ int sh;
    if (threadIdx.x == 0) sh = 0;
    __syncthreads();
    int loc = 0;
    for (int i = threadIdx.x; i < 4096; i += 256) {  // 16 KB prefix, in-bounds for all encodings
        unsigned v = m[i];
        if (v == 0x3F800000u) loc |= 1;              // fp32 1.0 marker
        else if (v > 1u) loc |= 2;                   // packed-byte marker
        else if (v != 0u) loc |= (i & 1) ? 4 : 8;    // nonzero at odd / even word index
    }
    if (loc) atomicOr(&sh, loc);
    __syncthreads();
    if (threadIdx.x == 0) {
        int s = sh;
        int mode;
        if (s & 1) mode = 2;                          // fp32
        else if (s & 2) mode = 1;                     // uint8
        else if ((s & 8) && !(s & 4)) mode = 3;       // int64: ones only in (even) low words
        else mode = 0;                                // int32
        *flag = mode;
    }
}

__device__ __forceinline__ float eluf(float x) {
    return x > 0.f ? x : (__expf(x) - 1.f);
}

// ---- tiled 64x64 GEMM core: X(2048x512) @ W(512x512), 4x4 per thread ------
__device__ __forceinline__ void gemm_tile_512(
    const float* __restrict__ X, const float* __restrict__ W,
    int m0, int n0, float* xs, float4 acc[4]) {
    int tid = threadIdx.x;
    int tn = tid & 15, tm = tid >> 4;
    acc[0] = make_float4(0.f, 0.f, 0.f, 0.f);
    acc[1] = acc[0]; acc[2] = acc[0]; acc[3] = acc[0];
    for (int kc = 0; kc < 512; kc += 64) {
        __syncthreads();
#pragma unroll
        for (int j = 0; j < 4; j++) {
            int ml = tm + 16 * j;
            *(float4*)(xs + ml * 64 + tn * 4) =
                *(const float4*)(X + (size_t)(m0 + ml) * 512 + kc + tn * 4);
        }
        __syncthreads();
#pragma unroll 4
        for (int k4 = 0; k4 < 16; k4++) {
            float4 x0 = *(const float4*)(xs + (tm * 4 + 0) * 64 + k4 * 4);
            float4 x1 = *(const float4*)(xs + (tm * 4 + 1) * 64 + k4 * 4);
            float4 x2 = *(const float4*)(xs + (tm * 4 + 2) * 64 + k4 * 4);
            float4 x3 = *(const float4*)(xs + (tm * 4 + 3) * 64 + k4 * 4);
            const float* wr = W + (size_t)(kc + k4 * 4) * 512 + n0 + tn * 4;
#pragma unroll
            for (int kk = 0; kk < 4; kk++) {
                float4 w = *(const float4*)(wr + (size_t)kk * 512);
                float a0 = (kk == 0) ? x0.x : (kk == 1) ? x0.y : (kk == 2) ? x0.z : x0.w;
                float a1 = (kk == 0) ? x1.x : (kk == 1) ? x1.y : (kk == 2) ? x1.z : x1.w;
                float a2 = (kk == 0) ? x2.x : (kk == 1) ? x2.y : (kk == 2) ? x2.z : x2.w;
                float a3 = (kk == 0) ? x3.x : (kk == 1) ? x3.y : (kk == 2) ? x3.z : x3.w;
                acc[0].x += a0 * w.x; acc[0].y += a0 * w.y; acc[0].z += a0 * w.z; acc[0].w += a0 * w.w;
                acc[1].x += a1 * w.x; acc[1].y += a1 * w.y; acc[1].z += a1 * w.z; acc[1].w += a1 * w.w;
                acc[2].x += a2 * w.x; acc[2].y += a2 * w.y; acc[2].z += a2 * w.z; acc[2].w += a2 * w.w;
                acc[3].x += a3 * w.x; acc[3].y += a3 * w.y; acc[3].z += a3 * w.z; acc[3].w += a3 * w.w;
            }
        }
    }
}

// ---- K1: QKV projections, tiled. Q,V -> (b,h,tok,d); K -> K^T (b,h,d,tok) -
__global__ __launch_bounds__(256) void k_qkv_t(
    const float* __restrict__ x,
    const float* __restrict__ Wq, const float* __restrict__ Wk, const float* __restrict__ Wv,
    const float* __restrict__ bq, const float* __restrict__ bk, const float* __restrict__ bv,
    float* __restrict__ qb, float* __restrict__ kt, float* __restrict__ vb) {
    __shared__ __align__(16) float xs[64 * 64];
    int bx = blockIdx.x;
    int which = bx >> 8; bx &= 255;
    int m0 = (bx >> 3) * 64, n0 = (bx & 7) * 64;
    const float* W    = (which == 0) ? Wq : (which == 1) ? Wk : Wv;
    const float* bias = (which == 0) ? bq : (which == 1) ? bk : bv;
    float4 acc[4];
    gemm_tile_512(x, W, m0, n0, xs, acc);
    int tn = threadIdx.x & 15, tm = threadIdx.x >> 4;
    float4 bv4 = *(const float4*)(bias + n0 + tn * 4);
    int hh = n0 >> 6, d = tn * 4;        // n0 is 64-aligned -> single head per tile
#pragma unroll
    for (int r = 0; r < 4; r++) {
        int m = m0 + tm * 4 + r;
        int b = m >> 10, tok = m & 1023;
        float4 v = acc[r];
        v.x += bv4.x; v.y += bv4.y; v.z += bv4.z; v.w += bv4.w;
        if (which == 1) {
            // K^T: (b,h,d,tok)
            float* kth = kt + (size_t)(b * NHD + hh) * (HD * NN);
            kth[(size_t)(d + 0) * NN + tok] = v.x;
            kth[(size_t)(d + 1) * NN + tok] = v.y;
            kth[(size_t)(d + 2) * NN + tok] = v.z;
            kth[(size_t)(d + 3) * NN + tok] = v.w;
        } else {
            float* out = (which == 0) ? qb : vb;
            *(float4*)(out + (((size_t)(b * NHD + hh) * NN + tok) * HD + d)) = v;
        }
    }
}

// 2-col QK accumulate: one q float4 against 4 d-rows (float2 each)
#define QK2(QV, A0, A1)                                                        \
    A0 = fmaf(QV.x, k0v.x, fmaf(QV.y, k1v.x, fmaf(QV.z, k2v.x, fmaf(QV.w, k3v.x, A0)))); \
    A1 = fmaf(QV.x, k0v.y, fmaf(QV.y, k1v.y, fmaf(QV.z, k2v.y, fmaf(QV.w, k3v.y, A1))));

// 16-term dot of e[] with a w1t row held in 4 float4s
#define DOT16(E, R)                                                            \
    fmaf(E[15], wD.w, fmaf(E[14], wD.z, fmaf(E[13], wD.y, fmaf(E[12], wD.x,    \
    fmaf(E[11], wC.w, fmaf(E[10], wC.z, fmaf(E[9],  wC.y, fmaf(E[8],  wC.x,    \
    fmaf(E[7],  wB.w, fmaf(E[6],  wB.z, fmaf(E[5],  wB.y, fmaf(E[4],  wB.x,    \
    fmaf(E[3],  wA.w, fmaf(E[2],  wA.z, fmaf(E[1],  wA.y, fmaf(E[0],  wA.x, R))))))))))))))))

// ---- K2: FUSED edge-MLP bias (head-shared) + QK^T + mask -> UNNORMALIZED exp
// 8 tiles of 128 k-cols; 1 MLP eval/thread; QK 2 cols/lane.
// Unrolls BOUNDED (#pragma unroll 2) so the scheduler's load-hoisting stays
// under the 128-VGPR budget the backend insists on for 512-thread blocks:
// rounds 2-5 all spilled 0.8-2.5 GB to scratch from full unroll-and-hoist.
// Softmax normalization deferred to k_av2 (which reads every row anyway).
__global__ __launch_bounds__(512, 2) void k_fscore(
    const float* __restrict__ qb, const float* __restrict__ kt,
    const float* __restrict__ ef,
    const float* __restrict__ We1, const float* __restrict__ be1,
    const float* __restrict__ We2, const float* __restrict__ be2,
    const void* __restrict__ mask, const int* __restrict__ mode_p,
    float* __restrict__ attn) {
    __shared__ __align__(16) float w1t[16][16];      // [o][f]  (transposed We1)
    __shared__ __align__(16) float w2[16][8];        // [o][h]
    __shared__ __align__(16) float b1s[16];
    __shared__ __align__(16) float b2s[8];
    __shared__ __align__(16) float qs[8][4][64];     // 8 KB
    __shared__ __align__(16) float biasS[8][4][128]; // 16 KB (per-tile bias, masked)
    int tid = threadIdx.x;
    if (tid < 256) w1t[tid & 15][tid >> 4] = We1[tid];
    else if (tid < 384) { int u = tid - 256; w2[u >> 3][u & 7] = We2[u]; }
    else if (tid < 400) b1s[tid - 384] = be1[tid - 384];
    else if (tid < 408) b2s[tid - 400] = be2[tid - 400];

    // XCD-aware swizzle: each XCD gets 64 contiguous logical blocks (one b per XCD)
    int bid = blockIdx.x;
    int lb = (bid & 7) * 64 + (bid >> 3);
    int b = lb >> 8, q0 = (lb & 255) * 4;

    {   // load Q[8h][4q][64d]
        int h = tid >> 6, q = (tid >> 4) & 3, c = tid & 15;
        *(float4*)(&qs[h][q][4 * c]) =
            *(const float4*)(qb + (((size_t)(b * NHD + h) * NN + q0 + q) * HD + 4 * c));
    }
    __syncthreads();
    int mode = *mode_p;
    int wv = tid >> 6, lane = tid & 63;
    const float* kth = kt + (size_t)(b * NHD + wv) * (HD * NN);  // [d][tok]
    int mq = tid >> 7, mk = tid & 127;                           // MLP assignment
    const float* efq = ef + (((size_t)b * NN) + q0 + mq) * (NN * NE);
    size_t mrow = (((size_t)b * NN) + q0 + mq) * NN;
    size_t arow = ((size_t)(b * NHD + wv) * NN + q0) * NN;       // q-stride = NN

    for (int t = 0; t < 8; t++) {
        int k0 = t * 128 + mk;
        // ---------- MLP phase: 1 eval/thread, on-the-fly layer-2 ----------
        {
            float e0[16];
            {
                const f4* pe0 = (const f4*)(efq + (size_t)k0 * NE);
#pragma unroll
                for (int c = 0; c < 4; c++) {
                    f4 v0 = __builtin_nontemporal_load(pe0 + c);   // streaming
                    e0[4*c+0]=v0.x; e0[4*c+1]=v0.y; e0[4*c+2]=v0.z; e0[4*c+3]=v0.w;
                }
            }
            float acc0[8];
#pragma unroll
            for (int j = 0; j < 8; j++) acc0[j] = b2s[j];
#pragma unroll 2
            for (int o = 0; o < 16; o++) {
                float4 wA = *(const float4*)(&w1t[o][0]);
                float4 wB = *(const float4*)(&w1t[o][4]);
                float4 wC = *(const float4*)(&w1t[o][8]);
                float4 wD = *(const float4*)(&w1t[o][12]);
                float a0 = DOT16(e0, b1s[o]);
                float g0v = eluf(a0);
                float4 u0 = *(const float4*)(&w2[o][0]);
                float4 u1 = *(const float4*)(&w2[o][4]);
                acc0[0] = fmaf(g0v, u0.x, acc0[0]); acc0[1] = fmaf(g0v, u0.y, acc0[1]);
                acc0[2] = fmaf(g0v, u0.z, acc0[2]); acc0[3] = fmaf(g0v, u0.w, acc0[3]);
                acc0[4] = fmaf(g0v, u1.x, acc0[4]); acc0[5] = fmaf(g0v, u1.y, acc0[5]);
                acc0[6] = fmaf(g0v, u1.z, acc0[6]); acc0[7] = fmaf(g0v, u1.w, acc0[7]);
            }
            size_t p0i = mrow + k0;
            bool m0;
            if (mode == 3)      m0 = ((const unsigned int*)mask)[2 * p0i] != 0u;
            else if (mode == 2) m0 = ((const float*)mask)[p0i] != 0.0f;
            else if (mode == 1) m0 = ((const unsigned char*)mask)[p0i] != 0;
            else                m0 = ((const int*)mask)[p0i] != 0;
#pragma unroll
            for (int hh = 0; hh < 8; hh++)
                biasS[hh][mq][mk] = m0 ? -1e30f : acc0[hh];
        }
        __syncthreads();
        // ---------- QK phase: wave = head; lane covers 2 consecutive k ------
        {
            float a00=0.f,a01=0.f, a10=0.f,a11=0.f, a20=0.f,a21=0.f, a30=0.f,a31=0.f;
            const float* kb0 = kth + t * 128 + 2 * lane;
#pragma unroll 2
            for (int dc = 0; dc < 16; dc++) {
                float4 qv0 = *(const float4*)(&qs[wv][0][dc * 4]);
                float4 qv1 = *(const float4*)(&qs[wv][1][dc * 4]);
                float4 qv2 = *(const float4*)(&qs[wv][2][dc * 4]);
                float4 qv3 = *(const float4*)(&qs[wv][3][dc * 4]);
                float2 k0v = *(const float2*)(kb0 + (size_t)(dc * 4 + 0) * NN);
                float2 k1v = *(const float2*)(kb0 + (size_t)(dc * 4 + 1) * NN);
                float2 k2v = *(const float2*)(kb0 + (size_t)(dc * 4 + 2) * NN);
                float2 k3v = *(const float2*)(kb0 + (size_t)(dc * 4 + 3) * NN);
                QK2(qv0, a00, a01);
                QK2(qv1, a10, a11);
                QK2(qv2, a20, a21);
                QK2(qv3, a30, a31);
            }
            float2 b0 = *(const float2*)(&biasS[wv][0][2 * lane]);
            float2 b1 = *(const float2*)(&biasS[wv][1][2 * lane]);
            float2 b2 = *(const float2*)(&biasS[wv][2][2 * lane]);
            float2 b3 = *(const float2*)(&biasS[wv][3][2 * lane]);
            f2 p0, p1, p2, p3;
            p0.x = __expf(fmaf(a00, 0.125f, b0.x)); p0.y = __expf(fmaf(a01, 0.125f, b0.y));
            p1.x = __expf(fmaf(a10, 0.125f, b1.x)); p1.y = __expf(fmaf(a11, 0.125f, b1.y));
            p2.x = __expf(fmaf(a20, 0.125f, b2.x)); p2.y = __expf(fmaf(a21, 0.125f, b2.y));
            p3.x = __expf(fmaf(a30, 0.125f, b3.x)); p3.y = __expf(fmaf(a31, 0.125f, b3.y));
            size_t kc = (size_t)t * 128 + 2 * lane;
            *(f2*)(attn + arow + 0 * NN + kc) = p0;
            *(f2*)(attn + arow + 1 * NN + kc) = p1;
            *(f2*)(attn + arow + 2 * NN + kc) = p2;
            *(f2*)(attn + arow + 3 * NN + kc) = p3;
        }
        __syncthreads();
    }
}

// ---- K3: attn @ V with deferred softmax normalization ---------------------
// Wave per (b,h, 8 q-rows), lane = d.  Pass 1: accumulate AV and row sums
// (attn holds unnormalized exp).  Then scale AV by 1/sum and write oattn;
// pass 2 normalizes the attn rows in place (wave-owned, no races).
__global__ __launch_bounds__(256) void k_av2(
    float* __restrict__ attn, const float* __restrict__ vb,
    float* __restrict__ oattn) {
    int w = blockIdx.x * 4 + (threadIdx.x >> 6);
    int lane = threadIdx.x & 63;
    int bh = w >> 7;
    int q0 = (w & 127) * 8;
    float* ar = attn + ((size_t)bh * NN + q0) * NN;
    const float* vbh = vb + (size_t)bh * (NN * HD);
    float acc[8] = {0.f, 0.f, 0.f, 0.f, 0.f, 0.f, 0.f, 0.f};
    float sum[8] = {0.f, 0.f, 0.f, 0.f, 0.f, 0.f, 0.f, 0.f};
#pragma unroll 2
    for (int k = 0; k < NN; k += 4) {
        float4 a[8];
#pragma unroll
        for (int r = 0; r < 8; r++) a[r] = *(const float4*)(ar + (size_t)r * NN + k);
        float v0 = vbh[(k + 0) * HD + lane];
        float v1 = vbh[(k + 1) * HD + lane];
        float v2 = vbh[(k + 2) * HD + lane];
        float v3 = vbh[(k + 3) * HD + lane];
#pragma unroll
        for (int r = 0; r < 8; r++) {
            acc[r] += a[r].x * v0;
            acc[r] += a[r].y * v1;
            acc[r] += a[r].z * v2;
            acc[r] += a[r].w * v3;
            sum[r] += (a[r].x + a[r].y) + (a[r].z + a[r].w);
        }
    }
    int b = bh >> 3, hh = bh & 7;
#pragma unroll
    for (int r = 0; r < 8; r++) {
        float inv = (sum[r] > 0.f) ? 1.f / sum[r] : 0.f;   // fully-masked -> zeros
        oattn[(size_t)(b * NN + q0 + r) * HID + hh * 64 + lane] = acc[r] * inv;
        // pass 2: normalize this attn row in place (L2-hot from pass 1)
        float* row = ar + (size_t)r * NN;
        for (int k = 4 * lane; k < NN; k += 256) {
            float4 v = *(const float4*)(row + k);
            v.x *= inv; v.y *= inv; v.z *= inv; v.w *= inv;
            *(float4*)(row + k) = v;
        }
    }
}

// ---- K4: output projection, tiled --------------------------------------
__global__ __launch_bounds__(256) void k_oproj_t(
    const float* __restrict__ oa, const float* __restrict__ Wo,
    const float* __restrict__ bo, float* __restrict__ out) {
    __shared__ __align__(16) float xs[64 * 64];
    int bx = blockIdx.x;
    int m0 = (bx >> 3) * 64, n0 = (bx & 7) * 64;
    float4 acc[4];
    gemm_tile_512(oa, Wo, m0, n0, xs, acc);
    int tn = threadIdx.x & 15, tm = threadIdx.x >> 4;
    float4 bv4 = *(const float4*)(bo + n0 + tn * 4);
#pragma unroll
    for (int r = 0; r < 4; r++) {
        int m = m0 + tm * 4 + r;
        float4 v = acc[r];
        v.x += bv4.x; v.y += bv4.y; v.z += bv4.z; v.w += bv4.w;
        *(float4*)(out + (size_t)m * HID + n0 + tn * 4) = v;
    }
}

extern "C" void kernel_launch(void* const* d_in, const int* in_sizes, int n_in,
                              void* d_out, int out_size, void* d_ws, size_t ws_size,
                              hipStream_t stream) {
    (void)in_sizes; (void)n_in; (void)out_size; (void)ws_size;
    const float* x   = (const float*)d_in[0];
    const float* ef  = (const float*)d_in[1];
    const void*  msk = d_in[2];
    const float* Wq  = (const float*)d_in[3];
    const float* bq  = (const float*)d_in[4];
    const float* Wk  = (const float*)d_in[5];
    const float* bk  = (const float*)d_in[6];
    const float* Wv  = (const float*)d_in[7];
    const float* bv  = (const float*)d_in[8];
    const float* Wo  = (const float*)d_in[9];
    const float* bo  = (const float*)d_in[10];
    const float* We1 = (const float*)d_in[11];
    const float* be1 = (const float*)d_in[12];
    const float* We2 = (const float*)d_in[13];
    const float* be2 = (const float*)d_in[14];

    char* ws = (char*)d_ws;
    float* qb    = (float*)(ws + 0);          // 4 MB  (b,h,tok,d)
    float* kt    = (float*)(ws + 4194304);    // 4 MB  K^T (b,h,d,tok)
    float* vb    = (float*)(ws + 8388608);    // 4 MB  (b,h,tok,d)
    float* oattn = (float*)(ws + 12582912);   // 4 MB  (b,tok, h*64+d)
    int*   flag  = (int*)(ws + 16777216);     // 4 B

    float* out0 = (float*)d_out;
    float* attn = out0 + (size_t)NB * NN * HID;  // output 1: (B,H,N,N) fp32

    k_maskdet<<<1, 256, 0, stream>>>((const unsigned int*)msk, flag);
    k_qkv_t<<<768, 256, 0, stream>>>(x, Wq, Wk, Wv, bq, bk, bv, qb, kt, vb);
    k_fscore<<<512, 512, 0, stream>>>(qb, kt, ef, We1, be1, We2, be2, msk, flag, attn);
    k_av2<<<512, 256, 0, stream>>>(attn, vb, oattn);
    k_oproj_t<<<256, 256, 0, stream>>>(oattn, Wo, bo, out0);
}

// Round 7
// 654.571 us; speedup vs baseline: 2.0622x; 1.0629x over previous
//
#include <hip/hip_runtime.h>

#define NB 2
#define NN 1024
#define HID 512
#define NHD 8
#define HD 64
#define NE 16

typedef float f4 __attribute__((ext_vector_type(4)));
typedef float f2 __attribute__((ext_vector_type(2)));

// ---- K0: mask dtype detection: 0=int32, 1=uint8-packed, 2=fp32, 3=int64 ----
__global__ __launch_bounds__(256) void k_maskdet(const unsigned int* __restrict__ m,
                                                 int* __restrict__ flag) {
    __shared__ int sh;
    if (threadIdx.x == 0) sh = 0;
    __syncthreads();
    int loc = 0;
    for (int i = threadIdx.x; i < 4096; i += 256) {  // 16 KB prefix, in-bounds for all encodings
        unsigned v = m[i];
        if (v == 0x3F800000u) loc |= 1;              // fp32 1.0 marker
        else if (v > 1u) loc |= 2;                   // packed-byte marker
        else if (v != 0u) loc |= (i & 1) ? 4 : 8;    // nonzero at odd / even word index
    }
    if (loc) atomicOr(&sh, loc);
    __syncthreads();
    if (threadIdx.x == 0) {
        int s = sh;
        int mode;
        if (s & 1) mode = 2;                          // fp32
        else if (s & 2) mode = 1;                     // uint8
        else if ((s & 8) && !(s & 4)) mode = 3;       // int64: ones only in (even) low words
        else mode = 0;                                // int32
        *flag = mode;
    }
}

__device__ __forceinline__ float eluf(float x) {
    return x > 0.f ? x : (__expf(x) - 1.f);
}

// ---- tiled 64x64 GEMM core: X(2048x512) @ W(512x512), 4x4 per thread ------
__device__ __forceinline__ void gemm_tile_512(
    const float* __restrict__ X, const float* __restrict__ W,
    int m0, int n0, float* xs, float4 acc[4]) {
    int tid = threadIdx.x;
    int tn = tid & 15, tm = tid >> 4;
    acc[0] = make_float4(0.f, 0.f, 0.f, 0.f);
    acc[1] = acc[0]; acc[2] = acc[0]; acc[3] = acc[0];
    for (int kc = 0; kc < 512; kc += 64) {
        __syncthreads();
#pragma unroll
        for (int j = 0; j < 4; j++) {
            int ml = tm + 16 * j;
            *(float4*)(xs + ml * 64 + tn * 4) =
                *(const float4*)(X + (size_t)(m0 + ml) * 512 + kc + tn * 4);
        }
        __syncthreads();
#pragma unroll 4
        for (int k4 = 0; k4 < 16; k4++) {
            float4 x0 = *(const float4*)(xs + (tm * 4 + 0) * 64 + k4 * 4);
            float4 x1 = *(const float4*)(xs + (tm * 4 + 1) * 64 + k4 * 4);
            float4 x2 = *(const float4*)(xs + (tm * 4 + 2) * 64 + k4 * 4);
            float4 x3 = *(const float4*)(xs + (tm * 4 + 3) * 64 + k4 * 4);
            const float* wr = W + (size_t)(kc + k4 * 4) * 512 + n0 + tn * 4;
#pragma unroll
            for (int kk = 0; kk < 4; kk++) {
                float4 w = *(const float4*)(wr + (size_t)kk * 512);
                float a0 = (kk == 0) ? x0.x : (kk == 1) ? x0.y : (kk == 2) ? x0.z : x0.w;
                float a1 = (kk == 0) ? x1.x : (kk == 1) ? x1.y : (kk == 2) ? x1.z : x1.w;
                float a2 = (kk == 0) ? x2.x : (kk == 1) ? x2.y : (kk == 2) ? x2.z : x2.w;
                float a3 = (kk == 0) ? x3.x : (kk == 1) ? x3.y : (kk == 2) ? x3.z : x3.w;
                acc[0].x += a0 * w.x; acc[0].y += a0 * w.y; acc[0].z += a0 * w.z; acc[0].w += a0 * w.w;
                acc[1].x += a1 * w.x; acc[1].y += a1 * w.y; acc[1].z += a1 * w.z; acc[1].w += a1 * w.w;
                acc[2].x += a2 * w.x; acc[2].y += a2 * w.y; acc[2].z += a2 * w.z; acc[2].w += a2 * w.w;
                acc[3].x += a3 * w.x; acc[3].y += a3 * w.y; acc[3].z += a3 * w.z; acc[3].w += a3 * w.w;
            }
        }
    }
}

// ---- K1: QKV projections, tiled. Q,V -> (b,h,tok,d); K -> K^T (b,h,d,tok) -
__global__ __launch_bounds__(256) void k_qkv_t(
    const float* __restrict__ x,
    const float* __restrict__ Wq, const float* __restrict__ Wk, const float* __restrict__ Wv,
    const float* __restrict__ bq, const float* __restrict__ bk, const float* __restrict__ bv,
    float* __restrict__ qb, float* __restrict__ kt, float* __restrict__ vb) {
    __shared__ __align__(16) float xs[64 * 64];
    int bx = blockIdx.x;
    int which = bx >> 8; bx &= 255;
    int m0 = (bx >> 3) * 64, n0 = (bx & 7) * 64;
    const float* W    = (which == 0) ? Wq : (which == 1) ? Wk : Wv;
    const float* bias = (which == 0) ? bq : (which == 1) ? bk : bv;
    float4 acc[4];
    gemm_tile_512(x, W, m0, n0, xs, acc);
    int tn = threadIdx.x & 15, tm = threadIdx.x >> 4;
    float4 bv4 = *(const float4*)(bias + n0 + tn * 4);
    int hh = n0 >> 6, d = tn * 4;        // n0 is 64-aligned -> single head per tile
#pragma unroll
    for (int r = 0; r < 4; r++) {
        int m = m0 + tm * 4 + r;
        int b = m >> 10, tok = m & 1023;
        float4 v = acc[r];
        v.x += bv4.x; v.y += bv4.y; v.z += bv4.z; v.w += bv4.w;
        if (which == 1) {
            // K^T: (b,h,d,tok)
            float* kth = kt + (size_t)(b * NHD + hh) * (HD * NN);
            kth[(size_t)(d + 0) * NN + tok] = v.x;
            kth[(size_t)(d + 1) * NN + tok] = v.y;
            kth[(size_t)(d + 2) * NN + tok] = v.z;
            kth[(size_t)(d + 3) * NN + tok] = v.w;
        } else {
            float* out = (which == 0) ? qb : vb;
            *(float4*)(out + (((size_t)(b * NHD + hh) * NN + tok) * HD + d)) = v;
        }
    }
}

// 2-col QK accumulate: one q float4 against 4 d-rows (float2 each)
#define QK2(QV, A0, A1)                                                        \
    A0 = fmaf(QV.x, k0v.x, fmaf(QV.y, k1v.x, fmaf(QV.z, k2v.x, fmaf(QV.w, k3v.x, A0)))); \
    A1 = fmaf(QV.x, k0v.y, fmaf(QV.y, k1v.y, fmaf(QV.z, k2v.y, fmaf(QV.w, k3v.y, A1))));

// 16-term dot of e[] with a w1t row held in 4 float4s
#define DOT16(E, R)                                                            \
    fmaf(E[15], wD.w, fmaf(E[14], wD.z, fmaf(E[13], wD.y, fmaf(E[12], wD.x,    \
    fmaf(E[11], wC.w, fmaf(E[10], wC.z, fmaf(E[9],  wC.y, fmaf(E[8],  wC.x,    \
    fmaf(E[7],  wB.w, fmaf(E[6],  wB.z, fmaf(E[5],  wB.y, fmaf(E[4],  wB.x,    \
    fmaf(E[3],  wA.w, fmaf(E[2],  wA.z, fmaf(E[1],  wA.y, fmaf(E[0],  wA.x, R))))))))))))))))

// ---- K2: FUSED edge-MLP bias (head-shared) + QK^T + mask -> UNNORMALIZED exp
// 8 tiles of 128 k-cols; 1 MLP eval/thread; QK 2 cols/lane.
// Unrolls BOUNDED (#pragma unroll 2) so the scheduler's load-hoisting stays
// under the 128-VGPR budget the backend insists on for 512-thread blocks:
// rounds 2-5 all spilled 0.8-2.5 GB to scratch from full unroll-and-hoist.
// Softmax normalization deferred to k_av2 (which reads every row anyway).
__global__ __launch_bounds__(512, 2) void k_fscore(
    const float* __restrict__ qb, const float* __restrict__ kt,
    const float* __restrict__ ef,
    const float* __restrict__ We1, const float* __restrict__ be1,
    const float* __restrict__ We2, const float* __restrict__ be2,
    const void* __restrict__ mask, const int* __restrict__ mode_p,
    float* __restrict__ attn) {
    __shared__ __align__(16) float w1t[16][16];      // [o][f]  (transposed We1)
    __shared__ __align__(16) float w2[16][8];        // [o][h]
    __shared__ __align__(16) float b1s[16];
    __shared__ __align__(16) float b2s[8];
    __shared__ __align__(16) float qs[8][4][64];     // 8 KB
    __shared__ __align__(16) float biasS[8][4][128]; // 16 KB (per-tile bias, masked)
    int tid = threadIdx.x;
    if (tid < 256) w1t[tid & 15][tid >> 4] = We1[tid];
    else if (tid < 384) { int u = tid - 256; w2[u >> 3][u & 7] = We2[u]; }
    else if (tid < 400) b1s[tid - 384] = be1[tid - 384];
    else if (tid < 408) b2s[tid - 400] = be2[tid - 400];

    // XCD-aware swizzle: each XCD gets 64 contiguous logical blocks (one b per XCD)
    int bid = blockIdx.x;
    int lb = (bid & 7) * 64 + (bid >> 3);
    int b = lb >> 8, q0 = (lb & 255) * 4;

    {   // load Q[8h][4q][64d]
        int h = tid >> 6, q = (tid >> 4) & 3, c = tid & 15;
        *(float4*)(&qs[h][q][4 * c]) =
            *(const float4*)(qb + (((size_t)(b * NHD + h) * NN + q0 + q) * HD + 4 * c));
    }
    __syncthreads();
    int mode = *mode_p;
    int wv = tid >> 6, lane = tid & 63;
    const float* kth = kt + (size_t)(b * NHD + wv) * (HD * NN);  // [d][tok]
    int mq = tid >> 7, mk = tid & 127;                           // MLP assignment
    const float* efq = ef + (((size_t)b * NN) + q0 + mq) * (NN * NE);
    size_t mrow = (((size_t)b * NN) + q0 + mq) * NN;
    size_t arow = ((size_t)(b * NHD + wv) * NN + q0) * NN;       // q-stride = NN

    for (int t = 0; t < 8; t++) {
        int k0 = t * 128 + mk;
        // ---------- MLP phase: 1 eval/thread, on-the-fly layer-2 ----------
        {
            float e0[16];
            {
                const f4* pe0 = (const f4*)(efq + (size_t)k0 * NE);
#pragma unroll
                for (int c = 0; c < 4; c++) {
                    f4 v0 = __builtin_nontemporal_load(pe0 + c);   // streaming
                    e0[4*c+0]=v0.x; e0[4*c+1]=v0.y; e0[4*c+2]=v0.z; e0[4*c+3]=v0.w;
                }
            }
            float acc0[8];
#pragma unroll
            for (int j = 0; j < 8; j++) acc0[j] = b2s[j];
#pragma unroll 2
            for (int o = 0; o < 16; o++) {
                float4 wA = *(const float4*)(&w1t[o][0]);
                float4 wB = *(const float4*)(&w1t[o][4]);
                float4 wC = *(const float4*)(&w1t[o][8]);
                float4 wD = *(const float4*)(&w1t[o][12]);
                float a0 = DOT16(e0, b1s[o]);
                float g0v = eluf(a0);
                float4 u0 = *(const float4*)(&w2[o][0]);
                float4 u1 = *(const float4*)(&w2[o][4]);
                acc0[0] = fmaf(g0v, u0.x, acc0[0]); acc0[1] = fmaf(g0v, u0.y, acc0[1]);
                acc0[2] = fmaf(g0v, u0.z, acc0[2]); acc0[3] = fmaf(g0v, u0.w, acc0[3]);
                acc0[4] = fmaf(g0v, u1.x, acc0[4]); acc0[5] = fmaf(g0v, u1.y, acc0[5]);
                acc0[6] = fmaf(g0v, u1.z, acc0[6]); acc0[7] = fmaf(g0v, u1.w, acc0[7]);
            }
            size_t p0i = mrow + k0;
            bool m0;
            if (mode == 3)      m0 = ((const unsigned int*)mask)[2 * p0i] != 0u;
            else if (mode == 2) m0 = ((const float*)mask)[p0i] != 0.0f;
            else if (mode == 1) m0 = ((const unsigned char*)mask)[p0i] != 0;
            else                m0 = ((const int*)mask)[p0i] != 0;
#pragma unroll
            for (int hh = 0; hh < 8; hh++)
                biasS[hh][mq][mk] = m0 ? -1e30f : acc0[hh];
        }
        __syncthreads();
        // ---------- QK phase: wave = head; lane covers 2 consecutive k ------
        {
            float a00=0.f,a01=0.f, a10=0.f,a11=0.f, a20=0.f,a21=0.f, a30=0.f,a31=0.f;
            const float* kb0 = kth + t * 128 + 2 * lane;
#pragma unroll 2
            for (int dc = 0; dc < 16; dc++) {
                float4 qv0 = *(const float4*)(&qs[wv][0][dc * 4]);
                float4 qv1 = *(const float4*)(&qs[wv][1][dc * 4]);
                float4 qv2 = *(const float4*)(&qs[wv][2][dc * 4]);
                float4 qv3 = *(const float4*)(&qs[wv][3][dc * 4]);
                float2 k0v = *(const float2*)(kb0 + (size_t)(dc * 4 + 0) * NN);
                float2 k1v = *(const float2*)(kb0 + (size_t)(dc * 4 + 1) * NN);
                float2 k2v = *(const float2*)(kb0 + (size_t)(dc * 4 + 2) * NN);
                float2 k3v = *(const float2*)(kb0 + (size_t)(dc * 4 + 3) * NN);
                QK2(qv0, a00, a01);
                QK2(qv1, a10, a11);
                QK2(qv2, a20, a21);
                QK2(qv3, a30, a31);
            }
            float2 b0 = *(const float2*)(&biasS[wv][0][2 * lane]);
            float2 b1 = *(const float2*)(&biasS[wv][1][2 * lane]);
            float2 b2 = *(const float2*)(&biasS[wv][2][2 * lane]);
            float2 b3 = *(const float2*)(&biasS[wv][3][2 * lane]);
            f2 p0, p1, p2, p3;
            p0.x = __expf(fmaf(a00, 0.125f, b0.x)); p0.y = __expf(fmaf(a01, 0.125f, b0.y));
            p1.x = __expf(fmaf(a10, 0.125f, b1.x)); p1.y = __expf(fmaf(a11, 0.125f, b1.y));
            p2.x = __expf(fmaf(a20, 0.125f, b2.x)); p2.y = __expf(fmaf(a21, 0.125f, b2.y));
            p3.x = __expf(fmaf(a30, 0.125f, b3.x)); p3.y = __expf(fmaf(a31, 0.125f, b3.y));
            size_t kc = (size_t)t * 128 + 2 * lane;
            *(f2*)(attn + arow + 0 * NN + kc) = p0;
            *(f2*)(attn + arow + 1 * NN + kc) = p1;
            *(f2*)(attn + arow + 2 * NN + kc) = p2;
            *(f2*)(attn + arow + 3 * NN + kc) = p3;
        }
        __syncthreads();
    }
}

// ---- K3: attn @ V with deferred softmax normalization ---------------------
// Wave per (b,h, 4 q-rows), lane = d.  4096 waves = 16/CU (was 8/CU with
// 8 rows/wave: occupancy 20%, VALUBusy 32% -> latency-bound; same traffic).
// Pass 1: accumulate AV + row sums (attn holds unnormalized exp); scale by
// 1/sum, write oattn; pass 2 normalizes attn rows in place (wave-owned).
__global__ __launch_bounds__(256) void k_av2(
    float* __restrict__ attn, const float* __restrict__ vb,
    float* __restrict__ oattn) {
    // XCD swizzle: 1024 blocks -> 128 contiguous per XCD (2 heads' V per L2)
    int bid = blockIdx.x;
    int lb = (bid & 7) * 128 + (bid >> 3);
    int w = lb * 4 + (threadIdx.x >> 6);
    int lane = threadIdx.x & 63;
    int bh = w >> 8;
    int q0 = (w & 255) * 4;
    float* ar = attn + ((size_t)bh * NN + q0) * NN;
    const float* vbh = vb + (size_t)bh * (NN * HD);
    float acc[4] = {0.f, 0.f, 0.f, 0.f};
    float sum[4] = {0.f, 0.f, 0.f, 0.f};
#pragma unroll 2
    for (int k = 0; k < NN; k += 4) {
        float4 a[4];
#pragma unroll
        for (int r = 0; r < 4; r++) a[r] = *(const float4*)(ar + (size_t)r * NN + k);
        float v0 = vbh[(k + 0) * HD + lane];
        float v1 = vbh[(k + 1) * HD + lane];
        float v2 = vbh[(k + 2) * HD + lane];
        float v3 = vbh[(k + 3) * HD + lane];
#pragma unroll
        for (int r = 0; r < 4; r++) {
            acc[r] += a[r].x * v0;
            acc[r] += a[r].y * v1;
            acc[r] += a[r].z * v2;
            acc[r] += a[r].w * v3;
            sum[r] += (a[r].x + a[r].y) + (a[r].z + a[r].w);
        }
    }
    int b = bh >> 3, hh = bh & 7;
#pragma unroll
    for (int r = 0; r < 4; r++) {
        float inv = (sum[r] > 0.f) ? 1.f / sum[r] : 0.f;   // fully-masked -> zeros
        oattn[(size_t)(b * NN + q0 + r) * HID + hh * 64 + lane] = acc[r] * inv;
        // pass 2: normalize this attn row in place (L2/L3-hot from pass 1)
        float* row = ar + (size_t)r * NN;
#pragma unroll
        for (int k = 4 * lane; k < NN; k += 256) {
            float4 v = *(const float4*)(row + k);
            v.x *= inv; v.y *= inv; v.z *= inv; v.w *= inv;
            *(float4*)(row + k) = v;
        }
    }
}

// ---- K4: output projection, tiled --------------------------------------
__global__ __launch_bounds__(256) void k_oproj_t(
    const float* __restrict__ oa, const float* __restrict__ Wo,
    const float* __restrict__ bo, float* __restrict__ out) {
    __shared__ __align__(16) float xs[64 * 64];
    int bx = blockIdx.x;
    int m0 = (bx >> 3) * 64, n0 = (bx & 7) * 64;
    float4 acc[4];
    gemm_tile_512(oa, Wo, m0, n0, xs, acc);
    int tn = threadIdx.x & 15, tm = threadIdx.x >> 4;
    float4 bv4 = *(const float4*)(bo + n0 + tn * 4);
#pragma unroll
    for (int r = 0; r < 4; r++) {
        int m = m0 + tm * 4 + r;
        float4 v = acc[r];
        v.x += bv4.x; v.y += bv4.y; v.z += bv4.z; v.w += bv4.w;
        *(float4*)(out + (size_t)m * HID + n0 + tn * 4) = v;
    }
}

extern "C" void kernel_launch(void* const* d_in, const int* in_sizes, int n_in,
                              void* d_out, int out_size, void* d_ws, size_t ws_size,
                              hipStream_t stream) {
    (void)in_sizes; (void)n_in; (void)out_size; (void)ws_size;
    const float* x   = (const float*)d_in[0];
    const float* ef  = (const float*)d_in[1];
    const void*  msk = d_in[2];
    const float* Wq  = (const float*)d_in[3];
    const float* bq  = (const float*)d_in[4];
    const float* Wk  = (const float*)d_in[5];
    const float* bk  = (const float*)d_in[6];
    const float* Wv  = (const float*)d_in[7];
    const float* bv  = (const float*)d_in[8];
    const float* Wo  = (const float*)d_in[9];
    const float* bo  = (const float*)d_in[10];
    const float* We1 = (const float*)d_in[11];
    const float* be1 = (const float*)d_in[12];
    const float* We2 = (const float*)d_in[13];
    const float* be2 = (const float*)d_in[14];

    char* ws = (char*)d_ws;
    float* qb    = (float*)(ws + 0);          // 4 MB  (b,h,tok,d)
    float* kt    = (float*)(ws + 4194304);    // 4 MB  K^T (b,h,d,tok)
    float* vb    = (float*)(ws + 8388608);    // 4 MB  (b,h,tok,d)
    float* oattn = (float*)(ws + 12582912);   // 4 MB  (b,tok, h*64+d)
    int*   flag  = (int*)(ws + 16777216);     // 4 B

    float* out0 = (float*)d_out;
    float* attn = out0 + (size_t)NB * NN * HID;  // output 1: (B,H,N,N) fp32

    k_maskdet<<<1, 256, 0, stream>>>((const unsigned int*)msk, flag);
    k_qkv_t<<<768, 256, 0, stream>>>(x, Wq, Wk, Wv, bq, bk, bv, qb, kt, vb);
    k_fscore<<<512, 512, 0, stream>>>(qb, kt, ef, We1, be1, We2, be2, msk, flag, attn);
    k_av2<<<1024, 256, 0, stream>>>(attn, vb, oattn);
    k_oproj_t<<<256, 256, 0, stream>>>(oattn, Wo, bo, out0);
}